// Round 2
// baseline (109.631 us; speedup 1.0000x reference)
//
#include <hip/hip_runtime.h>

#define NROWS 8192
#define DDIM  64
#define KNN   32
#define MAXIT 100

// alpha/beta arrive as 1-element arrays; robust to int32 or float32 encoding.
__device__ __forceinline__ float scalar_val(const void* p) {
    int iv = *(const int*)p;
    if (iv > -1000000 && iv < 1000000) return (float)iv;
    return *(const float*)p;
}

// Kernel 1: pure memset of A at full HBM write bandwidth.
__global__ __launch_bounds__(256) void zero_A_kernel(float4* __restrict__ A4) {
    const int total4 = NROWS * NROWS / 4;            // 16,777,216
    const int stride = gridDim.x * 256;
    const float4 z = make_float4(0.f, 0.f, 0.f, 0.f);
    for (int i = blockIdx.x * 256 + threadIdx.x; i < total4; i += stride)
        A4[i] = z;
}

// Kernel 2: distances -> simplex projection -> dedupe -> scatter + embs + Y copy.
// Runs after zero_A (stream-ordered); scatter overwrites zeros.
__global__ __launch_bounds__(256) void school_compute_kernel(
    const float* __restrict__ Y,
    const float* __restrict__ semH,
    const float* __restrict__ orthoH,
    const int*   __restrict__ idx,
    const void*  alpha_p,
    const void*  beta_p,
    float* __restrict__ embs,   // N*D
    float* __restrict__ A,      // N*N (pre-zeroed)
    float* __restrict__ Yout)   // N*D
{
    __shared__ float w_s[8][KNN];
    __shared__ int   col_s[8][KNN];

    const int tid  = threadIdx.x;
    const int j    = tid & 31;      // neighbor index within row
    const int r    = tid >> 5;      // row-within-block, 0..7
    const int row0 = blockIdx.x * 8;
    const int row  = row0 + r;

    // ---- Phase 1: distances for (row, neighbor j) ----
    const int col = idx[row * 64 + 1 + j];   // idxa0 = idx[:, 1:33]

    float df = 0.f, dx = 0.f;
    {
        const float4* y0 = (const float4*)(Y + (size_t)row * DDIM);
        const float4* y1 = (const float4*)(Y + (size_t)col * DDIM);
        const float4* o0 = (const float4*)(orthoH + (size_t)row * DDIM);
        const float4* o1 = (const float4*)(orthoH + (size_t)col * DDIM);
        #pragma unroll
        for (int q = 0; q < DDIM / 4; ++q) {
            float4 a = y0[q], b = y1[q];
            float e0 = a.x - b.x, e1 = a.y - b.y, e2 = a.z - b.z, e3 = a.w - b.w;
            df += e0 * e0 + e1 * e1 + e2 * e2 + e3 * e3;
            float4 c = o0[q], d = o1[q];
            float f0 = c.x - d.x, f1 = c.y - d.y, f2 = c.z - d.z, f3 = c.w - d.w;
            dx += f0 * f0 + f1 * f1 + f2 * f2 + f3 * f3;
        }
    }
    df = sqrtf(df + 1e-8f);
    dx = sqrtf(dx + 1e-8f);

    const float alpha = scalar_val(alpha_p);
    const float beta  = scalar_val(beta_p);
    const float ad = -(dx + beta * df) / (2.f * alpha);

    // ---- Phase 2: simplex projection (row = 32 lanes of this half-wave) ----
    float s = ad;
    #pragma unroll
    for (int m = 1; m <= 16; m <<= 1) s += __shfl_xor(s, m, 64);
    const float v0 = ad - s * (1.f / 32.f) + (1.f / 32.f);

    float lam = 0.f;
    #pragma unroll 1
    for (int it = 0; it < MAXIT; ++it) {
        float v1 = v0 - lam;
        float p = v1 > 0.f ? v1 : 0.f;   // where(pos, v1, 0)
        float c = v1 > 0.f ? 1.f : 0.f;  // pos count
        #pragma unroll
        for (int m = 1; m <= 16; m <<= 1) {
            p += __shfl_xor(p, m, 64);
            c += __shfl_xor(c, m, 64);
        }
        float nl = lam + (p - 1.f) / fmaxf(c, 1.f);
        bool conv = (nl == lam);     // exact fixed point -> identical to 100 iters
        lam = nl;
        if (__all(conv ? 1 : 0)) break;
    }
    const float w = fmaxf(v0 - lam, 0.f);

    // ---- Phase 3: dedupe (np fancy-assignment: last j wins) ----
    col_s[r][j] = col;               // same-wave LDS visibility
    bool dead = false;
    for (int jj = j + 1; jj < 32; ++jj)
        dead |= (col_s[r][jj] == col);
    w_s[r][j] = dead ? 0.f : w;      // dead entries contribute 0 to A@H

    // ---- Phase 4: scatter surviving entries into (pre-zeroed) A ----
    if (!dead) A[(size_t)row * NROWS + col] = w;

    __syncthreads();                 // LDS visibility (cheap; no store-drain now)

    // ---- Phase 5: embs_hom[row] = sum_j w_j * semH[col_j]  (coalesced) ----
    {
        float2 acc = make_float2(0.f, 0.f);
        const float2* H2 = (const float2*)semH;
        #pragma unroll 4
        for (int jj = 0; jj < KNN; ++jj) {
            float wv = w_s[r][jj];
            int   c  = col_s[r][jj];
            float2 h = H2[(size_t)c * 32 + j];   // lane j -> dims 2j,2j+1
            acc.x += wv * h.x;
            acc.y += wv * h.y;
        }
        ((float2*)embs)[(size_t)row * 32 + j] = acc;
    }

    // ---- Phase 6: Y passthrough (block's own 8 rows, coalesced float2) ----
    {
        const float2* Y2 = (const float2*)(Y + (size_t)row0 * DDIM);
        float2* O2 = (float2*)(Yout + (size_t)row0 * DDIM);
        O2[tid] = Y2[tid];           // 256 threads x 8B = 8 rows x 64 floats
    }
}

extern "C" void kernel_launch(void* const* d_in, const int* in_sizes, int n_in,
                              void* d_out, int out_size, void* d_ws, size_t ws_size,
                              hipStream_t stream) {
    const float* Y      = (const float*)d_in[0];
    const float* semH   = (const float*)d_in[1];
    const float* orthoH = (const float*)d_in[2];
    const int*   idx    = (const int*)d_in[3];
    const void*  alpha  = d_in[4];
    const void*  beta   = d_in[5];

    float* out  = (float*)d_out;
    float* embs = out;                                   // N*D
    float* A    = out + (size_t)NROWS * DDIM;            // N*N
    float* Yout = A + (size_t)NROWS * NROWS;             // N*D

    zero_A_kernel<<<4096, 256, 0, stream>>>((float4*)A);

    school_compute_kernel<<<NROWS / 8, 256, 0, stream>>>(
        Y, semH, orthoH, idx, alpha, beta, embs, A, Yout);
}

// Round 3
// 91.461 us; speedup vs baseline: 1.1987x; 1.1987x over previous
//
#include <hip/hip_runtime.h>

#define NROWS 8192
#define DDIM  64
#define KNN   32
#define MAXIT 100

// alpha/beta arrive as 1-element arrays; robust to int32 or float32 encoding.
__device__ __forceinline__ float scalar_val(const void* p) {
    int iv = *(const int*)p;
    if (iv > -1000000 && iv < 1000000) return (float)iv;
    return *(const float*)p;
}

// Fused: all LOADS + compute first, the 268MB zero-store stream LAST, then
// barrier + L2-hot scatter. No load ever waits behind the store stream
// (single in-order vmcnt), so compute overlaps other blocks' writes.
__global__ __launch_bounds__(256) void school_fused_kernel(
    const float* __restrict__ Y,
    const float* __restrict__ semH,
    const float* __restrict__ orthoH,
    const int*   __restrict__ idx,
    const void*  alpha_p,
    const void*  beta_p,
    float* __restrict__ embs,   // N*D
    float* __restrict__ A,      // N*N
    float* __restrict__ Yout)   // N*D
{
    __shared__ float w_s[8][KNN];
    __shared__ int   col_s[8][KNN];

    const int tid  = threadIdx.x;
    const int j    = tid & 31;      // neighbor index within row
    const int r    = tid >> 5;      // row-within-block, 0..7
    const int row0 = blockIdx.x * 8;
    const int row  = row0 + r;

    // ---- Phase 1: distances for (row, neighbor j) ----
    const int col = idx[row * 64 + 1 + j];   // idxa0 = idx[:, 1:33]

    float df = 0.f, dx = 0.f;
    {
        const float4* y0 = (const float4*)(Y + (size_t)row * DDIM);
        const float4* y1 = (const float4*)(Y + (size_t)col * DDIM);
        const float4* o0 = (const float4*)(orthoH + (size_t)row * DDIM);
        const float4* o1 = (const float4*)(orthoH + (size_t)col * DDIM);
        #pragma unroll
        for (int q = 0; q < DDIM / 4; ++q) {
            float4 a = y0[q], b = y1[q];
            float e0 = a.x - b.x, e1 = a.y - b.y, e2 = a.z - b.z, e3 = a.w - b.w;
            df += e0 * e0 + e1 * e1 + e2 * e2 + e3 * e3;
            float4 c = o0[q], d = o1[q];
            float f0 = c.x - d.x, f1 = c.y - d.y, f2 = c.z - d.z, f3 = c.w - d.w;
            dx += f0 * f0 + f1 * f1 + f2 * f2 + f3 * f3;
        }
    }
    df = sqrtf(df + 1e-8f);
    dx = sqrtf(dx + 1e-8f);

    const float alpha = scalar_val(alpha_p);
    const float beta  = scalar_val(beta_p);
    const float ad = -(dx + beta * df) / (2.f * alpha);

    // ---- Phase 2: simplex projection (row = 32 lanes of this half-wave) ----
    float s = ad;
    #pragma unroll
    for (int m = 1; m <= 16; m <<= 1) s += __shfl_xor(s, m, 64);
    const float v0 = ad - s * (1.f / 32.f) + (1.f / 32.f);

    float lam = 0.f;
    #pragma unroll 1
    for (int it = 0; it < MAXIT; ++it) {
        float v1 = v0 - lam;
        float p = v1 > 0.f ? v1 : 0.f;   // where(pos, v1, 0)
        float c = v1 > 0.f ? 1.f : 0.f;  // pos count
        #pragma unroll
        for (int m = 1; m <= 16; m <<= 1) {
            p += __shfl_xor(p, m, 64);
            c += __shfl_xor(c, m, 64);
        }
        float nl = lam + (p - 1.f) / fmaxf(c, 1.f);
        bool conv = (nl == lam);     // exact fixed point -> identical to 100 iters
        lam = nl;
        if (__all(conv ? 1 : 0)) break;
    }
    const float w = fmaxf(v0 - lam, 0.f);

    // ---- Phase 3: dedupe (np fancy-assignment: last j wins) ----
    col_s[r][j] = col;               // same-wave (half-wave) LDS visibility
    bool dead = false;
    for (int jj = j + 1; jj < 32; ++jj)
        dead |= (col_s[r][jj] == col);
    w_s[r][j] = dead ? 0.f : w;      // dead entries contribute 0 to A@H

    // ---- Phase 4: embs_hom[row] = sum_j w_j * semH[col_j]  (coalesced) ----
    {
        float2 acc = make_float2(0.f, 0.f);
        const float2* H2 = (const float2*)semH;
        #pragma unroll 4
        for (int jj = 0; jj < KNN; ++jj) {
            float wv = w_s[r][jj];
            int   c  = col_s[r][jj];
            float2 h = H2[(size_t)c * 32 + j];   // lane j -> dims 2j,2j+1
            acc.x += wv * h.x;
            acc.y += wv * h.y;
        }
        ((float2*)embs)[(size_t)row * 32 + j] = acc;
    }

    // ---- Phase 5: Y passthrough (block's own 8 rows, coalesced, L2-hot) ----
    {
        const float2* Y2 = (const float2*)(Y + (size_t)row0 * DDIM);
        float2* O2 = (float2*)(Yout + (size_t)row0 * DDIM);
        O2[tid] = Y2[tid];           // 256 threads x 8B = 8 rows x 64 floats
    }

    // ---- Phase 6: zero this block's 8 rows of A (streaming, LAST) ----
    {
        float4 z4 = make_float4(0.f, 0.f, 0.f, 0.f);
        float4* A4 = (float4*)(A + (size_t)row0 * NROWS);
        const int total4 = 8 * NROWS / 4;   // 16384 float4 per block
        #pragma unroll 8
        for (int i = tid; i < total4; i += 256) A4[i] = z4;
    }

    __syncthreads();                 // zero of own rows complete (cross-wave)

    // ---- Phase 7: scatter surviving entries into A (lines L2-hot) ----
    {
        bool dd = (w_s[r][j] == 0.f) && (col_s[r][j] == col) ? false : false;
        (void)dd;
        // recompute 'dead' cheaply from LDS? -- we still have it in a register
    }
    if (!dead) A[(size_t)row * NROWS + col] = w;
}

extern "C" void kernel_launch(void* const* d_in, const int* in_sizes, int n_in,
                              void* d_out, int out_size, void* d_ws, size_t ws_size,
                              hipStream_t stream) {
    const float* Y      = (const float*)d_in[0];
    const float* semH   = (const float*)d_in[1];
    const float* orthoH = (const float*)d_in[2];
    const int*   idx    = (const int*)d_in[3];
    const void*  alpha  = d_in[4];
    const void*  beta   = d_in[5];

    float* out  = (float*)d_out;
    float* embs = out;                                   // N*D
    float* A    = out + (size_t)NROWS * DDIM;            // N*N
    float* Yout = A + (size_t)NROWS * NROWS;             // N*D

    school_fused_kernel<<<NROWS / 8, 256, 0, stream>>>(
        Y, semH, orthoH, idx, alpha, beta, embs, A, Yout);
}

// Round 4
// 75.737 us; speedup vs baseline: 1.4475x; 1.2076x over previous
//
#include <hip/hip_runtime.h>

#define NROWS 8192
#define DDIM  64
#define KNN   32
#define MAXIT 100

// alpha/beta arrive as 1-element arrays; robust to int32 or float32 encoding.
__device__ __forceinline__ float scalar_val(const void* p) {
    int iv = *(const int*)p;
    if (iv > -1000000 && iv < 1000000) return (float)iv;
    return *(const float*)p;
}

// One block = 8 rows. Half-wave (32 lanes) per row end-to-end: distances,
// Newton simplex projection (tolerance early-exit), dedupe, embs, then zeros
// its OWN row of A and scatters after a per-wave vmcnt(0) -- no block barrier.
__global__ __launch_bounds__(256) void school_fused_kernel(
    const float* __restrict__ Y,
    const float* __restrict__ semH,
    const float* __restrict__ orthoH,
    const int*   __restrict__ idx,
    const void*  alpha_p,
    const void*  beta_p,
    float* __restrict__ embs,   // N*D
    float* __restrict__ A,      // N*N
    float* __restrict__ Yout)   // N*D
{
    __shared__ float w_s[8][KNN];
    __shared__ int   col_s[8][KNN];

    const int tid  = threadIdx.x;
    const int j    = tid & 31;      // neighbor index within row
    const int r    = tid >> 5;      // row-within-block, 0..7 (half-wave id)
    const int row0 = blockIdx.x * 8;
    const int row  = row0 + r;

    // ---- Phase 1: distances for (row, neighbor j) ----
    const int col = idx[row * 64 + 1 + j];   // idxa0 = idx[:, 1:33]

    float df = 0.f, dx = 0.f;
    {
        const float4* y0 = (const float4*)(Y + (size_t)row * DDIM);
        const float4* y1 = (const float4*)(Y + (size_t)col * DDIM);
        const float4* o0 = (const float4*)(orthoH + (size_t)row * DDIM);
        const float4* o1 = (const float4*)(orthoH + (size_t)col * DDIM);
        #pragma unroll
        for (int q = 0; q < DDIM / 4; ++q) {
            float4 a = y0[q], b = y1[q];
            float e0 = a.x - b.x, e1 = a.y - b.y, e2 = a.z - b.z, e3 = a.w - b.w;
            df += e0 * e0 + e1 * e1 + e2 * e2 + e3 * e3;
            float4 c = o0[q], d = o1[q];
            float f0 = c.x - d.x, f1 = c.y - d.y, f2 = c.z - d.z, f3 = c.w - d.w;
            dx += f0 * f0 + f1 * f1 + f2 * f2 + f3 * f3;
        }
    }
    df = sqrtf(df + 1e-8f);
    dx = sqrtf(dx + 1e-8f);

    const float alpha = scalar_val(alpha_p);
    const float beta  = scalar_val(beta_p);
    const float ad = -(dx + beta * df) / (2.f * alpha);

    // ---- Phase 2: simplex projection (32 lanes = one row) ----
    float s = ad;
    #pragma unroll
    for (int m = 1; m <= 16; m <<= 1) s += __shfl_xor(s, m, 64);
    const float v0 = ad - s * (1.f / 32.f) + (1.f / 32.f);

    // Newton on piecewise-linear f: converges in <10 iters once the active
    // set stabilizes; residual fp wobble is ~1e-8, so |step|<=1e-6 exits.
    // If steps stay large we run the full 100 iterations exactly like ref.
    float lam = 0.f;
    #pragma unroll 1
    for (int it = 0; it < MAXIT; ++it) {
        float v1 = v0 - lam;
        float p = v1 > 0.f ? v1 : 0.f;   // where(pos, v1, 0)
        float c = v1 > 0.f ? 1.f : 0.f;  // pos count
        #pragma unroll
        for (int m = 1; m <= 16; m <<= 1) {
            p += __shfl_xor(p, m, 64);
            c += __shfl_xor(c, m, 64);
        }
        float step = (p - 1.f) / fmaxf(c, 1.f);
        lam += step;
        if (__all(fabsf(step) <= 1e-6f ? 1 : 0)) break;
    }
    const float w = fmaxf(v0 - lam, 0.f);

    // ---- Phase 3: dedupe (np fancy-assignment: last j wins). Same half-wave
    // writes & reads these LDS slots -> wave-internal lgkmcnt ordering, no
    // barrier needed anywhere in this kernel.
    col_s[r][j] = col;
    bool dead = false;
    for (int jj = j + 1; jj < 32; ++jj)
        dead |= (col_s[r][jj] == col);
    w_s[r][j] = dead ? 0.f : w;      // dead entries contribute 0 to A@H

    // ---- Phase 4: embs_hom[row] = sum_j w_j * semH[col_j]  (coalesced) ----
    {
        float2 acc = make_float2(0.f, 0.f);
        const float2* H2 = (const float2*)semH;
        #pragma unroll 4
        for (int jj = 0; jj < KNN; ++jj) {
            float wv = w_s[r][jj];
            int   c  = col_s[r][jj];
            float2 h = H2[(size_t)c * 32 + j];   // lane j -> dims 2j,2j+1
            acc.x += wv * h.x;
            acc.y += wv * h.y;
        }
        ((float2*)embs)[(size_t)row * 32 + j] = acc;
    }

    // ---- Phase 5: Y passthrough (block's own 8 rows, coalesced, L2-hot) ----
    {
        const float2* Y2 = (const float2*)(Y + (size_t)row0 * DDIM);
        float2* O2 = (float2*)(Yout + (size_t)row0 * DDIM);
        O2[tid] = Y2[tid];           // 256 threads x 8B = 8 rows x 64 floats
    }

    // ---- Phase 6: zero OWN row of A (half-wave r -> row row0+r) ----
    {
        float4 z4 = make_float4(0.f, 0.f, 0.f, 0.f);
        float4* A4 = (float4*)(A + (size_t)row * NROWS);
        #pragma unroll 8
        for (int i = j; i < NROWS / 4; i += 32) A4[i] = z4;   // 64 stores/lane
    }

    // ---- Phase 7: drain THIS wave's stores, then scatter (L2-hot lines) ----
    asm volatile("s_waitcnt vmcnt(0)" ::: "memory");
    if (!dead) A[(size_t)row * NROWS + col] = w;
}

extern "C" void kernel_launch(void* const* d_in, const int* in_sizes, int n_in,
                              void* d_out, int out_size, void* d_ws, size_t ws_size,
                              hipStream_t stream) {
    const float* Y      = (const float*)d_in[0];
    const float* semH   = (const float*)d_in[1];
    const float* orthoH = (const float*)d_in[2];
    const int*   idx    = (const int*)d_in[3];
    const void*  alpha  = d_in[4];
    const void*  beta   = d_in[5];

    float* out  = (float*)d_out;
    float* embs = out;                                   // N*D
    float* A    = out + (size_t)NROWS * DDIM;            // N*N
    float* Yout = A + (size_t)NROWS * NROWS;             // N*D

    school_fused_kernel<<<NROWS / 8, 256, 0, stream>>>(
        Y, semH, orthoH, idx, alpha, beta, embs, A, Yout);
}